// Round 2
// baseline (5204.087 us; speedup 1.0000x reference)
//
#include <hip/hip_runtime.h>
#include <cstdint>
#include <math.h>

#define NEG_INF (-INFINITY)
#define MASK_VAL (-1e30f)

#define Bb   64
#define VN   100
#define QN   64
#define KN   64
#define VD   2048
#define QD   768
#define KGD  300
#define HH   1024
#define RR   32
#define HDm  32
#define GG   2
#define NBV  (Bb*VN)              /* 6400 */
#define LOGN ((size_t)NBV*QN*KN*GG) /* 52,428,800 */

// ---------------- proj: H[M,1024] = relu(A[M,K] @ W[K,1024] + b) ----------------
// BM=128, BN=64, BK=16, 256 threads, per-thread 8x4.
__global__ __launch_bounds__(256) void proj_kernel(const float* __restrict__ A,
                                                   const float* __restrict__ W,
                                                   const float* __restrict__ bias,
                                                   float* __restrict__ H,
                                                   int M, int K)
{
  __shared__ float As[16][132];   // [k][m], padded
  __shared__ float Ws[16][64];    // [k][n]
  int tid = threadIdx.x;
  int m0 = blockIdx.x * 128;
  int n0 = blockIdx.y * 64;
  int tm = tid >> 4, tn = tid & 15;
  float acc[8][4] = {};
  for (int k0 = 0; k0 < K; k0 += 16) {
#pragma unroll
    for (int l = 0; l < 2; l++) {
      int f = tid + l*256;
      int row = f >> 2, kq = (f & 3)*4;
      const float* src = A + (size_t)(m0+row)*K + k0 + kq;
      float x0,x1,x2,x3;
      if (k0 + kq + 4 <= K) { float4 v4 = *(const float4*)src; x0=v4.x; x1=v4.y; x2=v4.z; x3=v4.w; }
      else {
        x0 = (k0+kq+0<K)?src[0]:0.f; x1 = (k0+kq+1<K)?src[1]:0.f;
        x2 = (k0+kq+2<K)?src[2]:0.f; x3 = (k0+kq+3<K)?src[3]:0.f;
      }
      As[kq+0][row]=x0; As[kq+1][row]=x1; As[kq+2][row]=x2; As[kq+3][row]=x3;
    }
    { int krow = tid >> 4, cq = (tid & 15)*4;
      float4 v4 = make_float4(0.f,0.f,0.f,0.f);
      if (k0 + krow < K) v4 = *(const float4*)&W[(size_t)(k0+krow)*HH + n0 + cq];
      *(float4*)&Ws[krow][cq] = v4; }
    __syncthreads();
#pragma unroll
    for (int kk = 0; kk < 16; kk++) {
      float4 a0 = *(float4*)&As[kk][tm*8];
      float4 a1 = *(float4*)&As[kk][tm*8+4];
      float4 b4 = *(float4*)&Ws[kk][tn*4];
      float av[8] = {a0.x,a0.y,a0.z,a0.w,a1.x,a1.y,a1.z,a1.w};
      float bv4[4] = {b4.x,b4.y,b4.z,b4.w};
#pragma unroll
      for (int i=0;i<8;i++)
#pragma unroll
        for (int j=0;j<4;j++) acc[i][j] = fmaf(av[i], bv4[j], acc[i][j]);
    }
    __syncthreads();
  }
  float b0 = bias[n0+tn*4+0], b1 = bias[n0+tn*4+1], b2 = bias[n0+tn*4+2], b3 = bias[n0+tn*4+3];
#pragma unroll
  for (int i=0;i<8;i++) {
    float4 o;
    o.x = fmaxf(acc[i][0]+b0, 0.f); o.y = fmaxf(acc[i][1]+b1, 0.f);
    o.z = fmaxf(acc[i][2]+b2, 0.f); o.w = fmaxf(acc[i][3]+b3, 0.f);
    *(float4*)&H[(size_t)(m0+tm*8+i)*HH + n0 + tn*4] = o;
  }
}

// ---------------- mask: maskv[row] = (sum|v[row,:]| == 0) ----------------
__global__ __launch_bounds__(256) void mask_kernel(const float* __restrict__ v,
                                                   float* __restrict__ maskv)
{
  int row = blockIdx.x;
  int tid = threadIdx.x;
  const float* src = v + (size_t)row * VD;
  float s = 0.f;
  for (int i = tid; i < VD/4; i += 256) {
    float4 x = *(const float4*)&src[i*4];
    s += fabsf(x.x)+fabsf(x.y)+fabsf(x.z)+fabsf(x.w);
  }
#pragma unroll
  for (int off=32; off; off>>=1) s += __shfl_down(s, off);
  __shared__ float red[4];
  if ((tid & 63) == 0) red[tid>>6] = s;
  __syncthreads();
  if (tid == 0) maskv[row] = ((red[0]+red[1]+red[2]+red[3]) == 0.f) ? 1.f : 0.f;
}

// ---------------- stageA: u[rc][bv][y*64+z*2+g] = sum_x hv[bv][r*32+x]*T[r][x][y][z][g] ----
// grid (200, 8, RC): 32 bv-rows x 256 cols per wg.
__global__ __launch_bounds__(256) void stageA_kernel(const float* __restrict__ hv,
                                                     const float* __restrict__ Tg,
                                                     float* __restrict__ u, int r0)
{
  int rc = blockIdx.z; int r = r0 + rc;
  int m0 = blockIdx.x * 32;
  int c0 = blockIdx.y * 256;
  __shared__ float hs[32][36];    // [x][row]
  __shared__ float Ts[32][256];   // [x][c]
  int tid = threadIdx.x;
  { int row = tid >> 3, xq = (tid & 7)*4;
    float4 h4 = *(const float4*)&hv[(size_t)(m0+row)*HH + r*HDm + xq];
    hs[xq+0][row]=h4.x; hs[xq+1][row]=h4.y; hs[xq+2][row]=h4.z; hs[xq+3][row]=h4.w; }
#pragma unroll
  for (int l=0;l<8;l++){
    int f = tid + l*256; int x = f >> 6; int cq = (f & 63)*4;
    *(float4*)&Ts[x][cq] = *(const float4*)&Tg[(size_t)(r*HDm+x)*2048 + c0 + cq];
  }
  __syncthreads();
  int rgi = tid >> 5, cgi = tid & 31;
  float acc[4][8] = {};
#pragma unroll
  for (int x=0;x<32;x++){
    float4 h4 = *(float4*)&hs[x][rgi*4];
    float4 ta = *(float4*)&Ts[x][cgi*8];
    float4 tb = *(float4*)&Ts[x][cgi*8+4];
    float hv4[4] = {h4.x,h4.y,h4.z,h4.w};
    float tv[8]  = {ta.x,ta.y,ta.z,ta.w,tb.x,tb.y,tb.z,tb.w};
#pragma unroll
    for (int i=0;i<4;i++)
#pragma unroll
      for (int j=0;j<8;j++) acc[i][j] = fmaf(hv4[i], tv[j], acc[i][j]);
  }
#pragma unroll
  for (int i=0;i<4;i++){
    size_t off = ((size_t)rc*NBV + m0 + rgi*4 + i)*2048 + c0 + cgi*8;
    *(float4*)&u[off]   = make_float4(acc[i][0],acc[i][1],acc[i][2],acc[i][3]);
    *(float4*)&u[off+4] = make_float4(acc[i][4],acc[i][5],acc[i][6],acc[i][7]);
  }
}

// ---------------- triBC: per (b, v-pair): logits += sum_r (qt . u) . kt^T; softmax partials ----
__global__ __launch_bounds__(256) void triBC_kernel(const float* __restrict__ hq,
                                                    const float* __restrict__ hk,
                                                    const float* __restrict__ u,
                                                    const float* __restrict__ maskv,
                                                    float* __restrict__ logits,
                                                    float* __restrict__ pm, float* __restrict__ ps,
                                                    int r0, int RC, int isFirst, int isLast)
{
  int vt = blockIdx.x, b = blockIdx.y;
  int v0 = vt*2;
  int tid = threadIdx.x;
  __shared__ float qs[32][64];       // [y][q]
  __shared__ float ks[32][64];       // [z][k]
  __shared__ float as[2][32][64];    // [v][y][zg]
  __shared__ float wsm[64][64];      // [zg][q]
  float acc[2][2][4][4] = {};        // [v][g][qi][kj]
  for (int rc = 0; rc < RC; rc++){
    int r = r0 + rc;
#pragma unroll
    for (int l=0;l<2;l++){
      int f = tid + l*256; int qq = f & 63; int yq = (f >> 6)*4;
      float4 x = *(const float4*)&hq[(size_t)(b*QN+qq)*HH + r*HDm + yq];
      qs[yq+0][qq]=x.x; qs[yq+1][qq]=x.y; qs[yq+2][qq]=x.z; qs[yq+3][qq]=x.w;
      float4 y = *(const float4*)&hk[(size_t)(b*KN+qq)*HH + r*HDm + yq];
      ks[yq+0][qq]=y.x; ks[yq+1][qq]=y.y; ks[yq+2][qq]=y.z; ks[yq+3][qq]=y.w;
    }
    float* asf = &as[0][0][0];
#pragma unroll
    for (int l=0;l<4;l++){
      int f = tid + l*256; int vi = f >> 9; int idx = (f & 511)*4;
      *(float4*)&asf[vi*2048 + idx] =
        *(const float4*)&u[((size_t)rc*NBV + b*VN + v0 + vi)*2048 + idx];
    }
    __syncthreads();
#pragma unroll
    for (int vi=0; vi<2; vi++){
      // stage B: w[zg][q] = sum_y as[vi][y][zg] * qs[y][q]
      int zgg = tid >> 4, qg = tid & 15;
      float w4acc[4][4] = {};
#pragma unroll
      for (int y=0;y<32;y++){
        float4 a4 = *(float4*)&as[vi][y][zgg*4];
        float4 q4 = *(float4*)&qs[y][qg*4];
        float aa[4]={a4.x,a4.y,a4.z,a4.w}, qv[4]={q4.x,q4.y,q4.z,q4.w};
#pragma unroll
        for (int i=0;i<4;i++)
#pragma unroll
          for (int j=0;j<4;j++) w4acc[i][j] = fmaf(aa[i], qv[j], w4acc[i][j]);
      }
#pragma unroll
      for (int i=0;i<4;i++)
        *(float4*)&wsm[zgg*4+i][qg*4] = make_float4(w4acc[i][0],w4acc[i][1],w4acc[i][2],w4acc[i][3]);
      __syncthreads();
      // stage C: acc[vi][g][qi][kj] += sum_z w[z*2+g][q] * ks[z][k]
      int qg2 = tid >> 4, kg2 = tid & 15;
#pragma unroll
      for (int g=0; g<2; g++){
#pragma unroll
        for (int z=0; z<32; z++){
          float4 w4 = *(float4*)&wsm[z*2+g][qg2*4];
          float4 k4 = *(float4*)&ks[z][kg2*4];
          float wv[4]={w4.x,w4.y,w4.z,w4.w}, kv[4]={k4.x,k4.y,k4.z,k4.w};
#pragma unroll
          for (int i=0;i<4;i++)
#pragma unroll
            for (int j=0;j<4;j++) acc[vi][g][i][j] = fmaf(wv[i], kv[j], acc[vi][g][i][j]);
        }
      }
      __syncthreads();
    }
  }
  // epilogue: RMW/write logits, mask (finite sentinel, NOT -inf), online softmax partials
  int qg2 = tid >> 4, kg2 = tid & 15;
  float mk0 = maskv[b*VN + v0], mk1 = maskv[b*VN + v0 + 1];
  float mth[2] = {NEG_INF, NEG_INF}, sth[2] = {0.f, 0.f};
#pragma unroll
  for (int vi=0; vi<2; vi++){
    float mk = vi ? mk1 : mk0;
#pragma unroll
    for (int i=0;i<4;i++)
#pragma unroll
      for (int j=0;j<4;j++){
        size_t off = (((size_t)(b*VN + v0 + vi)*QN + qg2*4+i)*KN + kg2*4+j)*GG;
        float g0 = acc[vi][0][i][j], g1 = acc[vi][1][i][j];
        if (!isFirst){ float2 prev = *(const float2*)&logits[off]; g0 += prev.x; g1 += prev.y; }
        if (isLast && mk != 0.f){ g0 = MASK_VAL; g1 = MASK_VAL; }
        *(float2*)&logits[off] = make_float2(g0, g1);
        if (isLast){
          if (g0 > mth[0]){ sth[0] = sth[0]*__expf(mth[0]-g0) + 1.f; mth[0] = g0; }
          else sth[0] += __expf(g0 - mth[0]);
          if (g1 > mth[1]){ sth[1] = sth[1]*__expf(mth[1]-g1) + 1.f; mth[1] = g1; }
          else sth[1] += __expf(g1 - mth[1]);
        }
      }
  }
  if (isLast){
    float* rbuf = &wsm[0][0];   // 4096 floats available, need 1024
    __syncthreads();
    rbuf[tid] = mth[0]; rbuf[256+tid] = sth[0];
    rbuf[512+tid] = mth[1]; rbuf[768+tid] = sth[1];
    __syncthreads();
    for (int st=128; st>0; st>>=1){
      if (tid < st){
#pragma unroll
        for (int g=0; g<2; g++){
          int base = g*512;
          float ma = rbuf[base+tid], mb = rbuf[base+tid+st];
          float sa = rbuf[base+256+tid], sb = rbuf[base+256+tid+st];
          float mn = fmaxf(ma, mb);
          float sn = (mn == NEG_INF) ? 0.f : (sa*__expf(ma-mn) + sb*__expf(mb-mn));
          rbuf[base+tid] = mn; rbuf[base+256+tid] = sn;
        }
      }
      __syncthreads();
    }
    if (tid < 2){
      pm[((size_t)b*50 + vt)*2 + tid] = rbuf[tid*512];
      ps[((size_t)b*50 + vt)*2 + tid] = rbuf[tid*512 + 256];
    }
  }
}

// ---------------- combine per-(b,g) partials ----------------
__global__ __launch_bounds__(64) void combine_kernel(const float* __restrict__ pm,
                                                     const float* __restrict__ ps,
                                                     float* __restrict__ Mg, float* __restrict__ Sg)
{
  int bg = blockIdx.x; int b = bg >> 1, g = bg & 1;
  int lane = threadIdx.x;
  float m = NEG_INF, s = 0.f;
  if (lane < 50){ m = pm[((size_t)b*50 + lane)*2 + g]; s = ps[((size_t)b*50 + lane)*2 + g]; }
#pragma unroll
  for (int off=32; off; off>>=1){
    float m2 = __shfl_down(m, off);
    float s2 = __shfl_down(s, off);
    float mn = fmaxf(m, m2);
    float sn = (mn == NEG_INF) ? 0.f : (s*__expf(m-mn) + s2*__expf(m2-mn));
    m = mn; s = sn;
  }
  if (lane == 0){ Mg[b*2+g] = m; Sg[b*2+g] = s; }
}

// ---------------- p = exp(logits - M)/S ----------------
__global__ __launch_bounds__(256) void pwrite_kernel(const float* __restrict__ logits,
                                                     const float* __restrict__ Mg,
                                                     const float* __restrict__ Sg,
                                                     float* __restrict__ p)
{
  size_t stride = (size_t)gridDim.x * 256;
  const size_t n4 = LOGN/4;
  for (size_t idx = (size_t)blockIdx.x*256 + threadIdx.x; idx < n4; idx += stride){
    size_t e = idx*4;
    int b = (int)(e / ((size_t)VN*QN*KN*GG));
    float M0 = Mg[b*2], M1 = Mg[b*2+1];
    float iS0 = 1.f/Sg[b*2], iS1 = 1.f/Sg[b*2+1];
    float4 x = *(const float4*)&logits[e];
    float4 o;
    o.x = __expf(x.x - M0)*iS0;
    o.y = __expf(x.y - M1)*iS1;
    o.z = __expf(x.z - M0)*iS0;
    o.w = __expf(x.w - M1)*iS1;
    *(float4*)&p[e] = o;
  }
}

extern "C" void kernel_launch(void* const* d_in, const int* in_sizes, int n_in,
                              void* d_out, int out_size, void* d_ws, size_t ws_size,
                              hipStream_t stream)
{
  const float* v   = (const float*)d_in[0];
  const float* q   = (const float*)d_in[1];
  const float* kg  = (const float*)d_in[2];
  const float* Wv  = (const float*)d_in[3];
  const float* bv  = (const float*)d_in[4];
  const float* Wq  = (const float*)d_in[5];
  const float* bq  = (const float*)d_in[6];
  const float* Wkg = (const float*)d_in[7];
  const float* bkg = (const float*)d_in[8];
  const float* Tg  = (const float*)d_in[9];
  float* p_out  = (float*)d_out;
  float* logits = p_out + LOGN;
  float* ws = (float*)d_ws;

  float* h_v   = ws;                 // 6400x1024
  float* h_q   = ws + 6553600;       // 4096x1024
  float* h_k   = ws + 10747904;      // 4096x1024
  float* maskv = ws + 14942208;      // 6400
  float* pm    = ws + 14948608;      // 6400
  float* ps    = ws + 14955008;      // 6400
  float* Mg    = ws + 14961408;      // 128
  float* Sg    = ws + 14961536;      // 128
  const size_t UBASE = 14961664;
  const size_t USZ   = (size_t)NBV * 2048;  // one r-slice of u = 13,107,200 floats
  size_t wsf = ws_size / 4;

  int RC = 0; float* u = nullptr;
  if      (UBASE + 32*USZ <= wsf) RC = 32;
  else if (UBASE + 16*USZ <= wsf) RC = 16;
  else if (UBASE +  8*USZ <= wsf) RC = 8;
  if (RC) u = ws + UBASE;
  else { RC = 4; u = p_out; }   // p-region (= exactly 4*USZ floats) as scratch; overwritten at the end

  proj_kernel<<<dim3(50,16),256,0,stream>>>(v,  Wv,  bv,  h_v, NBV,    VD);
  proj_kernel<<<dim3(32,16),256,0,stream>>>(q,  Wq,  bq,  h_q, Bb*QN,  QD);
  proj_kernel<<<dim3(32,16),256,0,stream>>>(kg, Wkg, bkg, h_k, Bb*KN,  KGD);
  mask_kernel<<<NBV,256,0,stream>>>(v, maskv);

  for (int r0 = 0; r0 < RR; r0 += RC){
    stageA_kernel<<<dim3(200,8,RC),256,0,stream>>>(h_v, Tg, u, r0);
    triBC_kernel<<<dim3(50,Bb),256,0,stream>>>(h_q, h_k, u, maskv, logits, pm, ps,
                                               r0, RC, (r0==0)?1:0, (r0+RC>=RR)?1:0);
  }
  combine_kernel<<<128,64,0,stream>>>(pm, ps, Mg, Sg);
  pwrite_kernel<<<2048,256,0,stream>>>(logits, Mg, Sg, p_out);
}

// Round 3
// 1113.467 us; speedup vs baseline: 4.6738x; 4.6738x over previous
//
#include <hip/hip_runtime.h>
#include <cstdint>
#include <math.h>

#define MASK_VAL (-1e30f)

#define Bb   64
#define VN   100
#define QN   64
#define KN   64
#define VD   2048
#define QD   768
#define KGD  300
#define KGP  320            /* KGD padded to mult of 32 */
#define HH   1024
#define RR   32
#define HDm  32
#define GG   2
#define NBV  (Bb*VN)              /* 6400 */
#define LOGN ((size_t)NBV*QN*KN*GG) /* 52,428,800 */

typedef _Float16 half_t;
typedef _Float16 f16x8 __attribute__((ext_vector_type(8)));
typedef float    f32x4 __attribute__((ext_vector_type(4)));

#define MFMA_F16(a,b,c) __builtin_amdgcn_mfma_f32_16x16x32_f16(a,b,c,0,0,0)

// ---------------- cast2d: dst[r][c] = (r<Rs && c<Cs) ? (half)src[r*Cs+c] : 0 ----------------
__global__ __launch_bounds__(256) void cast2d_kernel(const float* __restrict__ src,
                                                     half_t* __restrict__ dst,
                                                     int Rd, int Cd, int Rs, int Cs)
{
  int idx = blockIdx.x*256 + threadIdx.x;
  int total = Rd*Cd;
  if (idx >= total) return;
  int r = idx / Cd, c = idx - r*Cd;
  float v = (r < Rs && c < Cs) ? src[(size_t)r*Cs + c] : 0.f;
  dst[idx] = (half_t)v;
}

// ---------------- castT: dst[n][k] = (k<Ks) ? (half)src[k][n] : 0 ; n in [0,1024) ----------
__global__ __launch_bounds__(256) void castT_kernel(const float* __restrict__ src,
                                                    half_t* __restrict__ dst,
                                                    int Kd, int Ks)
{
  int idx = blockIdx.x*256 + threadIdx.x;
  int total = HH*Kd;
  if (idx >= total) return;
  int n = idx / Kd, k = idx - n*Kd;
  dst[idx] = (half_t)((k < Ks) ? src[(size_t)k*HH + n] : 0.f);
}

// ---------------- permT: Tpp[r][ (zg*32+y)*32 + x ] = (half) T[(r*32+x)*2048 + y*64 + zg] ----
__global__ __launch_bounds__(256) void permT_kernel(const float* __restrict__ Tg,
                                                    half_t* __restrict__ Tpp)
{
  int idx = blockIdx.x*256 + threadIdx.x;
  if (idx >= 32*65536) return;
  int r = idx >> 16, rem = idx & 65535;
  int cp = rem >> 5, x = rem & 31;
  int y = cp & 31, zg = cp >> 5;
  Tpp[idx] = (half_t)Tg[((size_t)(r*32 + x) << 11) + y*64 + zg];
}

// ---------------- mask ----------------
__global__ __launch_bounds__(256) void mask_kernel(const float* __restrict__ v,
                                                   float* __restrict__ maskv)
{
  int row = blockIdx.x;
  int tid = threadIdx.x;
  const float* src = v + (size_t)row * VD;
  float s = 0.f;
  for (int i = tid; i < VD/4; i += 256) {
    float4 x = *(const float4*)&src[i*4];
    s += fabsf(x.x)+fabsf(x.y)+fabsf(x.z)+fabsf(x.w);
  }
#pragma unroll
  for (int off=32; off; off>>=1) s += __shfl_down(s, off);
  __shared__ float red[4];
  if ((tid & 63) == 0) red[tid>>6] = s;
  __syncthreads();
  if (tid == 0) maskv[row] = ((red[0]+red[1]+red[2]+red[3]) == 0.f) ? 1.f : 0.f;
}

// ---------------- proj (MFMA): H[M][1024] = relu(A[M][Kp] @ W + b), A fp16, Wt[n][k] fp16 ----
// grid (M/64, 16), 256 thr = 4 waves; wave = 16 rows x 64 cols.
__global__ __launch_bounds__(256) void proj_mfma_kernel(const half_t* __restrict__ A,
                                                        const half_t* __restrict__ Wt,
                                                        const float* __restrict__ bias,
                                                        half_t* __restrict__ H, int Kp)
{
  int w = threadIdx.x >> 6, lane = threadIdx.x & 63;
  int m0 = blockIdx.x*64 + w*16;
  int n0 = blockIdx.y*64;
  int lr = lane & 15, lc = lane >> 4;
  f32x4 acc[4];
#pragma unroll
  for (int nt=0;nt<4;nt++) acc[nt] = (f32x4)(0.f);
  const half_t* arow = A + (size_t)(m0 + lr)*Kp + lc*8;
  for (int k0 = 0; k0 < Kp; k0 += 32) {
    f16x8 a = *(const f16x8*)(arow + k0);
#pragma unroll
    for (int nt = 0; nt < 4; nt++) {
      f16x8 b = *(const f16x8*)(Wt + (size_t)(n0 + nt*16 + lr)*Kp + k0 + lc*8);
      acc[nt] = MFMA_F16(a, b, acc[nt]);
    }
  }
#pragma unroll
  for (int nt = 0; nt < 4; nt++) {
    float bb = bias[n0 + nt*16 + lr];
#pragma unroll
    for (int j = 0; j < 4; j++) {
      float vv = fmaxf(acc[nt][j] + bb, 0.f);
      H[(size_t)(m0 + lc*4 + j)*HH + n0 + nt*16 + lr] = (half_t)vv;
    }
  }
}

// ---------------- stageA (MFMA): u'[rc][bv][c'] = sum_x hv[bv][r*32+x] * T''[r][c'][x] ------
// grid (100, 8, RC), 256 thr = 4 waves; wave = 16 bv-rows x 256 c'.
__global__ __launch_bounds__(256) void stageA_mfma_kernel(const half_t* __restrict__ hv,
                                                          const half_t* __restrict__ Tpp,
                                                          half_t* __restrict__ u, int r0)
{
  int rc = blockIdx.z; int r = r0 + rc;
  int w = threadIdx.x >> 6, lane = threadIdx.x & 63;
  int m0 = blockIdx.x*64 + w*16;
  int n0 = blockIdx.y*256;
  int lr = lane & 15, lc = lane >> 4;
  f16x8 a = *(const f16x8*)(hv + (size_t)(m0 + lr)*HH + r*HDm + lc*8);
  const half_t* tb = Tpp + ((size_t)r << 16) + (size_t)n0*32 + lc*8;
  f32x4 acc[16];
#pragma unroll
  for (int nt = 0; nt < 16; nt++) {
    f16x8 b = *(const f16x8*)(tb + nt*16*32 + lr*32);
    acc[nt] = MFMA_F16(a, b, (f32x4)(0.f));
  }
  half_t* ub = u + ((size_t)rc*NBV + m0)*2048 + n0;
#pragma unroll
  for (int nt = 0; nt < 16; nt++) {
#pragma unroll
    for (int j = 0; j < 4; j++) {
      ub[(size_t)(lc*4 + j)*2048 + nt*16 + lr] = (half_t)acc[nt][j];
    }
  }
}

// ---------------- triBC (MFMA): per (b, 4 v): logits += sum_r (qt.u).kt^T; softmax partials --
// grid (25, 64), 256 thr = 4 waves, wave w -> bv = b*100 + vt*4 + w.
#define WSTRIDE 2080   /* halves per g-plane in w frag buffer (pad vs 2048 to split banks) */
__global__ __launch_bounds__(256,2) void triBC_mfma_kernel(const half_t* __restrict__ hq,
                                                           const half_t* __restrict__ hk,
                                                           const half_t* __restrict__ u,
                                                           const float* __restrict__ maskv,
                                                           float* __restrict__ logits,
                                                           float* __restrict__ pm,
                                                           float* __restrict__ ps,
                                                           int r0, int RC, int isFirst, int isLast)
{
  __shared__ __align__(16) half_t smem[2048 + 2048 + 4*2*WSTRIDE];
  half_t* qtf = smem;
  half_t* ktf = smem + 2048;
  int tid = threadIdx.x;
  int w = tid >> 6, lane = tid & 63;
  half_t* wme = smem + 4096 + w*(2*WSTRIDE);
  int vt = blockIdx.x, b = blockIdx.y;
  int bv = b*VN + vt*4 + w;
  int lr = lane & 15, lc = lane >> 4;

  f32x4 acc[2][4][4];
#pragma unroll
  for (int g=0;g<2;g++)
#pragma unroll
    for (int mt=0;mt<4;mt++)
#pragma unroll
      for (int nt=0;nt<4;nt++) acc[g][mt][nt] = (f32x4)(0.f);

  // staging map: 256 threads stage 64 rows x 32 halves (4 thr/row, 8 halves each)
  int srow = tid >> 2, sch = tid & 3;
  const half_t* qsrc = hq + (size_t)(b*QN + srow)*HH + sch*8;
  const half_t* ksrc = hk + (size_t)(b*KN + srow)*HH + sch*8;
  int sdst = (srow>>4)*512 + ((srow&15) + sch*16)*8;

  for (int rc = 0; rc < RC; rc++) {
    int r = r0 + rc;
    __syncthreads();                                   // prev rank's C done
    // issue u' fragment loads early (coalesced 1KB per tile)
    const half_t* up = u + ((size_t)rc*NBV + bv)*2048;
    f16x8 ub[4];
#pragma unroll
    for (int nt=0;nt<4;nt++) ub[nt] = *(const f16x8*)(up + (nt*16+lr)*HDm + lc*8);
    // stage qt/kt frag-major
    *(f16x8*)&qtf[sdst] = *(const f16x8*)(qsrc + r*HDm);
    *(f16x8*)&ktf[sdst] = *(const f16x8*)(ksrc + r*HDm);
    __syncthreads();
    // stage B: w[q][zg] = sum_y qt[q][y] * u[y][zg]
    f16x8 qa[4];
#pragma unroll
    for (int mt=0;mt<4;mt++) qa[mt] = *(const f16x8*)&qtf[mt*512 + lane*8];
#pragma unroll
    for (int nt=0;nt<4;nt++) {
      f32x4 wv[4];
#pragma unroll
      for (int mt=0;mt<4;mt++) wv[mt] = MFMA_F16(qa[mt], ub[nt], (f32x4)(0.f));
      // scatter to frag-major fp16: g = lr&1, slot j = lr>>1
#pragma unroll
      for (int mt=0;mt<4;mt++) {
#pragma unroll
        for (int j=0;j<4;j++) {
          int dst = (lr&1)*WSTRIDE + mt*512 + (lc*4 + j + nt*16)*8 + (lr>>1);
          wme[dst] = (half_t)wv[mt][j];
        }
      }
    }
    __syncthreads();
    // stage C: logits[q][k][g] += sum_z w_g[q][z] * kt[k][z]
    f16x8 bk[4];
#pragma unroll
    for (int nt=0;nt<4;nt++) bk[nt] = *(const f16x8*)&ktf[nt*512 + lane*8];
#pragma unroll
    for (int g=0;g<2;g++) {
      f16x8 am[4];
#pragma unroll
      for (int mt=0;mt<4;mt++) am[mt] = *(const f16x8*)&wme[g*WSTRIDE + mt*512 + lane*8];
#pragma unroll
      for (int mt=0;mt<4;mt++)
#pragma unroll
        for (int nt=0;nt<4;nt++)
          acc[g][mt][nt] = MFMA_F16(am[mt], bk[nt], acc[g][mt][nt]);
    }
  }

  // epilogue
  float mk = maskv[bv];
  float* lbase = logits + (size_t)bv*QN*KN*GG;
#pragma unroll
  for (int mt=0;mt<4;mt++)
#pragma unroll
    for (int nt=0;nt<4;nt++)
#pragma unroll
      for (int j=0;j<4;j++) {
        size_t off = ((size_t)(mt*16 + lc*4 + j)*KN + nt*16 + lr)*GG;
        float g0 = acc[0][mt][nt][j], g1 = acc[1][mt][nt][j];
        if (!isFirst) { float2 prev = *(const float2*)(lbase + off); g0 += prev.x; g1 += prev.y; }
        if (isLast && mk != 0.f) { g0 = MASK_VAL; g1 = MASK_VAL; }
        *(float2*)(lbase + off) = make_float2(g0, g1);
        acc[0][mt][nt][j] = g0; acc[1][mt][nt][j] = g1;
      }
  if (isLast) {
#pragma unroll
    for (int g=0; g<2; g++) {
      float mloc = acc[g][0][0][0];
#pragma unroll
      for (int mt=0;mt<4;mt++)
#pragma unroll
        for (int nt=0;nt<4;nt++)
#pragma unroll
          for (int j=0;j<4;j++) mloc = fmaxf(mloc, acc[g][mt][nt][j]);
      float sloc = 0.f;
#pragma unroll
      for (int mt=0;mt<4;mt++)
#pragma unroll
        for (int nt=0;nt<4;nt++)
#pragma unroll
          for (int j=0;j<4;j++) sloc += __expf(acc[g][mt][nt][j] - mloc);
#pragma unroll
      for (int off2=1; off2<64; off2<<=1) {
        float m2 = __shfl_xor(mloc, off2);
        float s2 = __shfl_xor(sloc, off2);
        float mn = fmaxf(mloc, m2);
        sloc = sloc*__expf(mloc-mn) + s2*__expf(m2-mn);
        mloc = mn;
      }
      if (lane == 0) { pm[(size_t)bv*GG + g] = mloc; ps[(size_t)bv*GG + g] = sloc; }
    }
  }
}

// ---------------- combine per-(b,g) partials over 100 v ----------------
__global__ __launch_bounds__(64) void combine_kernel(const float* __restrict__ pm,
                                                     const float* __restrict__ ps,
                                                     float* __restrict__ Mg, float* __restrict__ Sg)
{
  int bg = blockIdx.x; int b = bg >> 1, g = bg & 1;
  int lane = threadIdx.x;
  float m = pm[((size_t)b*VN + lane)*GG + g];
  float s = ps[((size_t)b*VN + lane)*GG + g];
  if (lane + 64 < VN) {
    float m2 = pm[((size_t)b*VN + lane + 64)*GG + g];
    float s2 = ps[((size_t)b*VN + lane + 64)*GG + g];
    float mn = fmaxf(m, m2);
    s = s*__expf(m-mn) + s2*__expf(m2-mn); m = mn;
  }
#pragma unroll
  for (int off=1; off<64; off<<=1) {
    float m2 = __shfl_xor(m, off);
    float s2 = __shfl_xor(s, off);
    float mn = fmaxf(m, m2);
    s = s*__expf(m-mn) + s2*__expf(m2-mn);
    m = mn;
  }
  if (lane == 0) { Mg[b*GG+g] = m; Sg[b*GG+g] = s; }
}

// ---------------- p = exp(logits - M)/S ----------------
__global__ __launch_bounds__(256) void pwrite_kernel(const float* __restrict__ logits,
                                                     const float* __restrict__ Mg,
                                                     const float* __restrict__ Sg,
                                                     float* __restrict__ p)
{
  size_t stride = (size_t)gridDim.x * 256;
  const size_t n4 = LOGN/4;
  for (size_t idx = (size_t)blockIdx.x*256 + threadIdx.x; idx < n4; idx += stride){
    size_t e = idx*4;
    int b = (int)(e / ((size_t)VN*QN*KN*GG));
    float M0 = Mg[b*2], M1 = Mg[b*2+1];
    float iS0 = 1.f/Sg[b*2], iS1 = 1.f/Sg[b*2+1];
    float4 x = *(const float4*)&logits[e];
    float4 o;
    o.x = __expf(x.x - M0)*iS0;
    o.y = __expf(x.y - M1)*iS1;
    o.z = __expf(x.z - M0)*iS0;
    o.w = __expf(x.w - M1)*iS1;
    *(float4*)&p[e] = o;
  }
}

extern "C" void kernel_launch(void* const* d_in, const int* in_sizes, int n_in,
                              void* d_out, int out_size, void* d_ws, size_t ws_size,
                              hipStream_t stream)
{
  const float* v   = (const float*)d_in[0];
  const float* q   = (const float*)d_in[1];
  const float* kg  = (const float*)d_in[2];
  const float* Wv  = (const float*)d_in[3];
  const float* bv  = (const float*)d_in[4];
  const float* Wq  = (const float*)d_in[5];
  const float* bq  = (const float*)d_in[6];
  const float* Wkg = (const float*)d_in[7];
  const float* bkg = (const float*)d_in[8];
  const float* Tg  = (const float*)d_in[9];
  float* p_out  = (float*)d_out;
  float* logits = p_out + LOGN;

  char* ws = (char*)d_ws;
  size_t off = 0;
  auto alloc = [&](size_t bytes) -> char* {
    char* ptr = ws + off;
    off = (off + bytes + 255) & ~(size_t)255;
    return ptr;
  };
  half_t* h_v16 = (half_t*)alloc((size_t)NBV*HH*2);
  half_t* h_q16 = (half_t*)alloc((size_t)Bb*QN*HH*2);
  half_t* h_k16 = (half_t*)alloc((size_t)Bb*KN*HH*2);
  half_t* v16   = (half_t*)alloc((size_t)NBV*VD*2);
  half_t* q16   = (half_t*)alloc((size_t)Bb*QN*QD*2);
  half_t* k16   = (half_t*)alloc((size_t)Bb*KN*KGP*2);
  half_t* Wvt   = (half_t*)alloc((size_t)HH*VD*2);
  half_t* Wqt   = (half_t*)alloc((size_t)HH*QD*2);
  half_t* Wkt   = (half_t*)alloc((size_t)HH*KGP*2);
  half_t* Tpp   = (half_t*)alloc((size_t)32*65536*2);
  float* maskv  = (float*)alloc((size_t)NBV*4);
  float* pm     = (float*)alloc((size_t)NBV*GG*4);
  float* ps     = (float*)alloc((size_t)NBV*GG*4);
  float* Mg     = (float*)alloc(128*4);
  float* Sg     = (float*)alloc(128*4);
  size_t WS_FIXED = off;
  const size_t USZB = (size_t)NBV*2048*2;   // 26,214,400 bytes per r-slice

  int RC; half_t* u;
  if      (WS_FIXED + 32*USZB <= ws_size) { RC = 32; u = (half_t*)(ws + off); }
  else if (WS_FIXED + 16*USZB <= ws_size) { RC = 16; u = (half_t*)(ws + off); }
  else if (WS_FIXED +  8*USZB <= ws_size) { RC =  8; u = (half_t*)(ws + off); }
  else { RC = 8; u = (half_t*)p_out; }      // p region = exactly 8 slices; rewritten at end

  auto nb = [](size_t total) { return (unsigned)((total + 255) / 256); };

  // casts / permute / mask
  cast2d_kernel<<<nb((size_t)NBV*VD),256,0,stream>>>(v,  v16, NBV,   VD,  NBV,   VD);
  cast2d_kernel<<<nb((size_t)Bb*QN*QD),256,0,stream>>>(q,  q16, Bb*QN, QD,  Bb*QN, QD);
  cast2d_kernel<<<nb((size_t)Bb*KN*KGP),256,0,stream>>>(kg, k16, Bb*KN, KGP, Bb*KN, KGD);
  castT_kernel<<<nb((size_t)HH*VD),256,0,stream>>>(Wv,  Wvt, VD,  VD);
  castT_kernel<<<nb((size_t)HH*QD),256,0,stream>>>(Wq,  Wqt, QD,  QD);
  castT_kernel<<<nb((size_t)HH*KGP),256,0,stream>>>(Wkg, Wkt, KGP, KGD);
  permT_kernel<<<nb((size_t)32*65536),256,0,stream>>>(Tg, Tpp);
  mask_kernel<<<NBV,256,0,stream>>>(v, maskv);

  // projections (MFMA)
  proj_mfma_kernel<<<dim3(NBV/64,16),256,0,stream>>>(v16, Wvt, bv,  h_v16, VD);
  proj_mfma_kernel<<<dim3(Bb*QN/64,16),256,0,stream>>>(q16, Wqt, bq,  h_q16, QD);
  proj_mfma_kernel<<<dim3(Bb*KN/64,16),256,0,stream>>>(k16, Wkt, bkg, h_k16, KGP);

  for (int r0 = 0; r0 < RR; r0 += RC) {
    stageA_mfma_kernel<<<dim3(100,8,RC),256,0,stream>>>(h_v16, Tpp, u, r0);
    triBC_mfma_kernel<<<dim3(25,Bb),256,0,stream>>>(h_q16, h_k16, u, maskv, logits, pm, ps,
                                                    r0, RC, (r0==0)?1:0, (r0+RC>=RR)?1:0);
  }
  combine_kernel<<<128,64,0,stream>>>(pm, ps, Mg, Sg);
  pwrite_kernel<<<2048,256,0,stream>>>(logits, Mg, Sg, p_out);
}